// Round 5
// baseline (825.186 us; speedup 1.0000x reference)
//
#include <hip/hip_runtime.h>
#include <hip/hip_bf16.h>

// GCN 3-layer + edge-MLP head. R5: single-atomic-pass capacity-bucket CSR,
// 4B/edge compressed edata (src:18b | sig_q14:14b), thread-per-node gathers.
//
// Algebra (verified R4): g = dinv (.) h ; raw_i = dinv_i*(g_i + sum_e sig_e*g_src)
// head: out[e] = p[a] + q[b]; p,q fused into layer-3 dense epilogue.

#define CAP 56               // bucket capacity; deg ~ Poisson(20), P(row>56) ~ 1e-10/node
#define QS 16384.0f          // 14-bit weight quantization
#define QINV (1.0f / 16384.0f)

__device__ __forceinline__ float sigmoidf_(float x) {
    return 1.0f / (1.0f + __expf(-x));
}

// ---- single pass: histogram + direct bucket fill (the only atomic kernel)
__global__ void fill_kernel(const int* __restrict__ src, const int* __restrict__ dst,
                            const float* __restrict__ ew, int* __restrict__ cnt,
                            unsigned* __restrict__ edata, int ne) {
    int e = blockIdx.x * blockDim.x + threadIdx.x;
    if (e >= ne) return;
    int d = dst[e];
    int off = atomicAdd(&cnt[d], 1);
    if (off < CAP) {
        float w = sigmoidf_(ew[e]);
        int q = (int)fminf(w * QS + 0.5f, 16383.0f);
        edata[(size_t)d * CAP + off] = (unsigned)src[e] | ((unsigned)q << 18);
    }
}

// ---- fused: dinv_i = rsqrt(1 + sum_row sig) ; g0 = dinv (.) (x @ W1)  (7 -> 8)
__global__ void degxw1_kernel(const float* __restrict__ x, const float* __restrict__ W,
                              const int* __restrict__ cnt, const unsigned* __restrict__ edata,
                              float* __restrict__ dinv, float* __restrict__ g, int n) {
    __shared__ float Ws[56];
    if (threadIdx.x < 56) Ws[threadIdx.x] = W[threadIdx.x];
    __syncthreads();
    int i = blockIdx.x * blockDim.x + threadIdx.x;
    if (i >= n) return;
    int c = min(cnt[i], CAP);
    const unsigned* row = edata + (size_t)i * CAP;
    unsigned qs = 0;
    for (int k = 0; k < c; ++k) qs += (row[k] >> 18);
    float dv = rsqrtf((float)qs * QINV + 1.0f);
    dinv[i] = dv;
    float xi[7];
#pragma unroll
    for (int k = 0; k < 7; ++k) xi[k] = x[(size_t)i * 7 + k];
#pragma unroll
    for (int o = 0; o < 8; ++o) {
        float acc = 0.0f;
#pragma unroll
        for (int k = 0; k < 7; ++k) acc = fmaf(xi[k], Ws[k * 8 + o], acc);
        g[(size_t)i * 8 + o] = acc * dv;
    }
}

// ---- thread-per-node gather-reduce: t = g[i] + sum sig*g[src]
// L1: out = dinv * relu(dinv*t + bias)  (g1 directly) ; else: out = dinv * t (raw)
template <int F, bool L1>
__global__ void gather_kernel(const float* __restrict__ g, const float* __restrict__ dinv,
                              const int* __restrict__ cnt, const unsigned* __restrict__ edata,
                              const float* __restrict__ bias, float* __restrict__ out, int n) {
    constexpr int C4 = F / 4;
    int i = blockIdx.x * blockDim.x + threadIdx.x;
    if (i >= n) return;
    int c = min(cnt[i], CAP);
    const unsigned* row = edata + (size_t)i * CAP;
    float4 acc[C4];
    const float4* gi = reinterpret_cast<const float4*>(g + (size_t)i * F);
#pragma unroll
    for (int j = 0; j < C4; ++j) acc[j] = gi[j];
    for (int k = 0; k < c; ++k) {
        unsigned v = row[k];
        int s = (int)(v & 0x3FFFFu);
        float w = (float)(v >> 18) * QINV;
        const float4* gs = reinterpret_cast<const float4*>(g + (size_t)s * F);
#pragma unroll
        for (int j = 0; j < C4; ++j) {
            float4 t = gs[j];
            acc[j].x = fmaf(t.x, w, acc[j].x);
            acc[j].y = fmaf(t.y, w, acc[j].y);
            acc[j].z = fmaf(t.z, w, acc[j].z);
            acc[j].w = fmaf(t.w, w, acc[j].w);
        }
    }
    float dv = dinv[i];
    float4* op = reinterpret_cast<float4*>(out + (size_t)i * F);
#pragma unroll
    for (int j = 0; j < C4; ++j) {
        if (L1) {
            acc[j].x = dv * fmaxf(dv * acc[j].x + bias[j * 4 + 0], 0.0f);
            acc[j].y = dv * fmaxf(dv * acc[j].y + bias[j * 4 + 1], 0.0f);
            acc[j].z = dv * fmaxf(dv * acc[j].z + bias[j * 4 + 2], 0.0f);
            acc[j].w = dv * fmaxf(dv * acc[j].w + bias[j * 4 + 3], 0.0f);
        } else {
            acc[j].x *= dv; acc[j].y *= dv; acc[j].z *= dv; acc[j].w *= dv;
        }
        op[j] = acc[j];
    }
}

// ---- dense + relu + dinv: out = dinv (.) relu(raw @ W + b)
template <int IN, int OUT>
__global__ void dense_kernel(const float* __restrict__ raw, const float* __restrict__ W,
                             const float* __restrict__ b, const float* __restrict__ dinv,
                             float* __restrict__ out, int n) {
    __shared__ float Ws[IN * OUT];
    __shared__ float bs[OUT];
    for (int k = threadIdx.x; k < IN * OUT; k += blockDim.x) Ws[k] = W[k];
    if (threadIdx.x < OUT) bs[threadIdx.x] = b[threadIdx.x];
    __syncthreads();
    int i = blockIdx.x * blockDim.x + threadIdx.x;
    if (i >= n) return;
    float xi[IN];
#pragma unroll
    for (int c = 0; c < IN / 4; ++c) {
        float4 v = *reinterpret_cast<const float4*>(raw + (size_t)i * IN + c * 4);
        xi[c * 4 + 0] = v.x; xi[c * 4 + 1] = v.y; xi[c * 4 + 2] = v.z; xi[c * 4 + 3] = v.w;
    }
    float dv = dinv[i];
#pragma unroll
    for (int o = 0; o < OUT; ++o) {
        float acc = bs[o];
#pragma unroll
        for (int k = 0; k < IN; ++k) acc = fmaf(xi[k], Ws[k * OUT + o], acc);
        out[(size_t)i * OUT + o] = dv * fmaxf(acc, 0.0f);
    }
}

// ---- layer-3 dense + head projection, head-weight fusion done in-block:
// wf = Wl1@Wl2 (64x3), bfv = bl1@Wl2 + bl2; h = relu(raw16@W3+b3);
// p = h@wf[0:32] + bfv; q = h@wf[32:64]; h3 never materialized.
__global__ void dense3_kernel(const float* __restrict__ raw, const float* __restrict__ W,
                              const float* __restrict__ b, const float* __restrict__ Wl1,
                              const float* __restrict__ bl1, const float* __restrict__ Wl2,
                              const float* __restrict__ bl2, float* __restrict__ pq, int n) {
    __shared__ float Ws[512];
    __shared__ float bs[32];
    __shared__ float wfs[192];
    __shared__ float bfs[3];
    for (int k = threadIdx.x; k < 512; k += blockDim.x) Ws[k] = W[k];
    if (threadIdx.x < 32) bs[threadIdx.x] = b[threadIdx.x];
    if (threadIdx.x < 192) {
        int f = threadIdx.x / 3, j = threadIdx.x % 3;
        float acc = 0.0f;
#pragma unroll
        for (int k = 0; k < 4; ++k) acc = fmaf(Wl1[f * 4 + k], Wl2[k * 3 + j], acc);
        wfs[threadIdx.x] = acc;
    }
    if (threadIdx.x < 3) {
        float acc = bl2[threadIdx.x];
#pragma unroll
        for (int k = 0; k < 4; ++k) acc = fmaf(bl1[k], Wl2[k * 3 + threadIdx.x], acc);
        bfs[threadIdx.x] = acc;
    }
    __syncthreads();
    int i = blockIdx.x * blockDim.x + threadIdx.x;
    if (i >= n) return;
    float xi[16];
#pragma unroll
    for (int c = 0; c < 4; ++c) {
        float4 v = *reinterpret_cast<const float4*>(raw + (size_t)i * 16 + c * 4);
        xi[c * 4 + 0] = v.x; xi[c * 4 + 1] = v.y; xi[c * 4 + 2] = v.z; xi[c * 4 + 3] = v.w;
    }
    float p0 = bfs[0], p1 = bfs[1], p2 = bfs[2];
    float q0 = 0.0f, q1 = 0.0f, q2 = 0.0f;
#pragma unroll
    for (int o = 0; o < 32; ++o) {
        float h = bs[o];
#pragma unroll
        for (int k = 0; k < 16; ++k) h = fmaf(xi[k], Ws[k * 32 + o], h);
        h = fmaxf(h, 0.0f);
        p0 = fmaf(h, wfs[o * 3 + 0], p0);
        p1 = fmaf(h, wfs[o * 3 + 1], p1);
        p2 = fmaf(h, wfs[o * 3 + 2], p2);
        q0 = fmaf(h, wfs[(32 + o) * 3 + 0], q0);
        q1 = fmaf(h, wfs[(32 + o) * 3 + 1], q1);
        q2 = fmaf(h, wfs[(32 + o) * 3 + 2], q2);
    }
    float4 P = {p0, p1, p2, 0.0f};
    float4 Q = {q0, q1, q2, 0.0f};
    *reinterpret_cast<float4*>(pq + (size_t)i * 8 + 0) = P;
    *reinterpret_cast<float4*>(pq + (size_t)i * 8 + 4) = Q;
}

// ---- head: out[e] = p[a] + q[b]
__global__ void head_kernel(const int* __restrict__ w2b, const float4* __restrict__ pq,
                            float* __restrict__ out, int nw) {
    int e = blockIdx.x * blockDim.x + threadIdx.x;
    if (e >= nw) return;
    int a = w2b[e];
    int b = w2b[(size_t)nw + e];
    float4 P = pq[(size_t)a * 2 + 0];
    float4 Q = pq[(size_t)b * 2 + 1];
    out[(size_t)e * 3 + 0] = P.x + Q.x;
    out[(size_t)e * 3 + 1] = P.y + Q.y;
    out[(size_t)e * 3 + 2] = P.z + Q.z;
}

extern "C" void kernel_launch(void* const* d_in, const int* in_sizes, int n_in,
                              void* d_out, int out_size, void* d_ws, size_t ws_size,
                              hipStream_t stream) {
    const float* x   = (const float*)d_in[0];
    const int* eidx  = (const int*)d_in[1];
    const int* w2b   = (const int*)d_in[2];
    const float* ew  = (const float*)d_in[3];
    const float* W1  = (const float*)d_in[4];
    const float* b1  = (const float*)d_in[5];
    const float* W2  = (const float*)d_in[6];
    const float* b2  = (const float*)d_in[7];
    const float* W3  = (const float*)d_in[8];
    const float* b3  = (const float*)d_in[9];
    const float* Wl1 = (const float*)d_in[10];
    const float* bl1 = (const float*)d_in[11];
    const float* Wl2 = (const float*)d_in[12];
    const float* bl2 = (const float*)d_in[13];
    float* out = (float*)d_out;

    const int n  = in_sizes[0] / 7;   // 200000
    const int ne = in_sizes[1] / 2;   // 4000000
    const int nw = in_sizes[2] / 2;   // 2000000
    const int* src = eidx;
    const int* dst = eidx + ne;

    // ---- workspace layout ----  (total = (2 + CAP + 40) * n floats ~= 78.4 MB)
    float*    ws    = (float*)d_ws;
    float*    dinv  = ws;                               // n
    int*      cnt   = (int*)(ws + n);                   // n
    unsigned* edata = (unsigned*)(ws + 2 * (size_t)n);  // n*CAP
    float*    A     = ws + (2 + CAP) * (size_t)n;       // 16n
    float*    B_    = A + (size_t)n * 16;               // 16n
    float*    pq    = B_ + (size_t)n * 16;              // 8n

    const int Bl = 256;
    auto blks = [&](long long t) { return (int)((t + Bl - 1) / Bl); };
    const int nb = blks(n);

    // 1. bucket fill (single atomic pass)
    (void)hipMemsetAsync(cnt, 0, (size_t)n * sizeof(int), stream);
    fill_kernel<<<blks(ne), Bl, 0, stream>>>(src, dst, ew, cnt, edata, ne);

    // 2. dinv + layer-1 pre-transform: A = g0
    degxw1_kernel<<<nb, Bl, 0, stream>>>(x, W1, cnt, edata, dinv, A, n);

    // 3. layer 1 gather: B = g1
    gather_kernel<8, true><<<nb, Bl, 0, stream>>>(A, dinv, cnt, edata, b1, B_, n);

    // 4. layer 2: A = raw2 ; B = g2
    gather_kernel<8, false><<<nb, Bl, 0, stream>>>(B_, dinv, cnt, edata, nullptr, A, n);
    dense_kernel<8, 16><<<nb, Bl, 0, stream>>>(A, W2, b2, dinv, B_, n);

    // 5. layer 3: A = raw3 ; pq = fused dense3 + head projection
    gather_kernel<16, false><<<nb, Bl, 0, stream>>>(B_, dinv, cnt, edata, nullptr, A, n);
    dense3_kernel<<<nb, Bl, 0, stream>>>(A, W3, b3, Wl1, bl1, Wl2, bl2, pq, n);

    // 6. head
    head_kernel<<<blks(nw), Bl, 0, stream>>>(w2b, (const float4*)pq, out, nw);
}

// Round 6
// 647.003 us; speedup vs baseline: 1.2754x; 1.2754x over previous
//
#include <hip/hip_runtime.h>
#include <hip/hip_bf16.h>

// GCN 3-layer + edge-MLP head. R6: counting-sort CSR build with LDS-aggregated
// atomics (no contended device atomics), then thread-per-node gathers.
//
// Build: bin = dst>>8 (256 nodes/bin). P1a: per-(bin,block) LDS histogram.
// S1/S2: scans -> per-(bin,block) offsets + bin bases. P1b: scatter into
// binned arrays, each (bin,block) run written by ONE block (no cross-XCD
// line ping-pong). P2: one block per bin builds node-sorted edata + C + dinv
// with LDS counters/cursors only.
//
// Algebra (verified R4/R5): g = dinv (.) h ; raw_i = dinv_i*(g_i + sum sig*g_src)
// head: out[e] = p[a] + q[b]; p,q fused into layer-3 dense epilogue.

#define NB1 256          // phase-1 blocks
#define NPB 256          // nodes per bin (= 1<<8)
#define MAXBINS 1024     // LDS sizing bound (nbins = ceil(n/256) = 782)
#define QS 16384.0f      // 14-bit weight quantization
#define QINV (1.0f / 16384.0f)

__device__ __forceinline__ float sigmoidf_(float x) {
    return 1.0f / (1.0f + __expf(-x));
}

// ---- P1a: per-(bin,block) histogram via LDS
__global__ void p1a_hist(const int* __restrict__ dst, int* __restrict__ bh,
                         int ne, int nbins, int chunk) {
    __shared__ int h[MAXBINS];
    for (int k = threadIdx.x; k < nbins; k += 256) h[k] = 0;
    __syncthreads();
    int base = blockIdx.x * chunk;
    int end = min(base + chunk, ne);
    for (int e = base + threadIdx.x; e < end; e += 256)
        atomicAdd(&h[dst[e] >> 8], 1);
    __syncthreads();
    for (int k = threadIdx.x; k < nbins; k += 256)
        bh[(size_t)k * NB1 + blockIdx.x] = h[k];
}

// ---- S1: per-bin exclusive scan over the NB1 block counts (in-place), emit bin totals
__global__ void s1_scan(int* __restrict__ bh, int* __restrict__ bintot) {
    __shared__ int tmp[NB1];
    int bin = blockIdx.x;
    int v = bh[(size_t)bin * NB1 + threadIdx.x];
    tmp[threadIdx.x] = v;
    __syncthreads();
    for (int o = 1; o < NB1; o <<= 1) {
        int t = (threadIdx.x >= o) ? tmp[threadIdx.x - o] : 0;
        __syncthreads();
        tmp[threadIdx.x] += t;
        __syncthreads();
    }
    bh[(size_t)bin * NB1 + threadIdx.x] = tmp[threadIdx.x] - v;  // exclusive
    if (threadIdx.x == NB1 - 1) bintot[bin] = tmp[NB1 - 1];
}

// ---- S2: exclusive scan of bin totals -> binbase; binbase[nbins] = ne
__global__ void s2_scan(const int* __restrict__ bintot, int* __restrict__ binbase,
                        int nbins, int ne) {
    __shared__ int tmp[1024];
    int tid = threadIdx.x;
    int v = (tid < nbins) ? bintot[tid] : 0;
    tmp[tid] = v;
    __syncthreads();
    for (int o = 1; o < 1024; o <<= 1) {
        int t = (tid >= o) ? tmp[tid - o] : 0;
        __syncthreads();
        tmp[tid] += t;
        __syncthreads();
    }
    if (tid < nbins) binbase[tid] = tmp[tid] - v;
    if (tid == 0) binbase[nbins] = ne;
}

// ---- P1b: scatter edges into binned arrays (block-exclusive runs)
__global__ void p1b_scatter(const int* __restrict__ src, const int* __restrict__ dst,
                            const float* __restrict__ ew, const int* __restrict__ bh,
                            const int* __restrict__ binbase, unsigned* __restrict__ blo,
                            unsigned char* __restrict__ bdl, int ne, int nbins, int chunk) {
    __shared__ int cur[MAXBINS];
    for (int k = threadIdx.x; k < nbins; k += 256)
        cur[k] = binbase[k] + bh[(size_t)k * NB1 + blockIdx.x];
    __syncthreads();
    int base = blockIdx.x * chunk;
    int end = min(base + chunk, ne);
    for (int e = base + threadIdx.x; e < end; e += 256) {
        int d = dst[e];
        float w = sigmoidf_(ew[e]);
        int q = (int)fminf(w * QS + 0.5f, 16383.0f);
        unsigned lo = (unsigned)src[e] | ((unsigned)q << 18);
        int pos = atomicAdd(&cur[d >> 8], 1);
        blo[pos] = lo;
        bdl[pos] = (unsigned char)(d & 255);
    }
}

// ---- P2: per-bin CSR finalize (LDS counters/scan/cursors; no global atomics)
__global__ void p2_build(const unsigned* __restrict__ blo, const unsigned char* __restrict__ bdl,
                         const int* __restrict__ binbase, unsigned* __restrict__ edata,
                         int* __restrict__ C, float* __restrict__ dinv,
                         int n, int ne, int nbins) {
    __shared__ int cnt[NPB];
    __shared__ int rs[NPB];
    __shared__ int curs[NPB];
    __shared__ unsigned qsum[NPB];
    int b = blockIdx.x;
    int E0 = binbase[b], E1 = binbase[b + 1];
    cnt[threadIdx.x] = 0;
    qsum[threadIdx.x] = 0;
    __syncthreads();
    for (int k = E0 + threadIdx.x; k < E1; k += 256)
        atomicAdd(&cnt[bdl[k]], 1);
    __syncthreads();
    int v = cnt[threadIdx.x];
    rs[threadIdx.x] = v;
    __syncthreads();
    for (int o = 1; o < NPB; o <<= 1) {
        int t = (threadIdx.x >= o) ? rs[threadIdx.x - o] : 0;
        __syncthreads();
        rs[threadIdx.x] += t;
        __syncthreads();
    }
    int excl = rs[threadIdx.x] - v;
    curs[threadIdx.x] = E0 + excl;
    int node = b * NPB + threadIdx.x;
    if (node < n) C[node] = E0 + excl;
    if (b == 0 && threadIdx.x == 0) C[n] = ne;
    __syncthreads();
    for (int k = E0 + threadIdx.x; k < E1; k += 256) {
        unsigned lo = blo[k];
        int dl = bdl[k];
        int pos = atomicAdd(&curs[dl], 1);
        edata[pos] = lo;
        atomicAdd(&qsum[dl], lo >> 18);
    }
    __syncthreads();
    if (node < n) dinv[node] = rsqrtf((float)qsum[threadIdx.x] * QINV + 1.0f);
}

// ---- layer-1 pre-transform: g0 = dinv (.) (x @ W1)   (7 -> 8)
__global__ void xw1_kernel(const float* __restrict__ x, const float* __restrict__ W,
                           const float* __restrict__ dinv, float* __restrict__ g, int n) {
    __shared__ float Ws[56];
    if (threadIdx.x < 56) Ws[threadIdx.x] = W[threadIdx.x];
    __syncthreads();
    int i = blockIdx.x * blockDim.x + threadIdx.x;
    if (i >= n) return;
    float xi[7];
#pragma unroll
    for (int k = 0; k < 7; ++k) xi[k] = x[(size_t)i * 7 + k];
    float dv = dinv[i];
#pragma unroll
    for (int o = 0; o < 8; ++o) {
        float acc = 0.0f;
#pragma unroll
        for (int k = 0; k < 7; ++k) acc = fmaf(xi[k], Ws[k * 8 + o], acc);
        g[(size_t)i * 8 + o] = acc * dv;
    }
}

// ---- thread-per-node gather-reduce over CSR row: t = g[i] + sum sig*g[src]
// L1: out = dinv * relu(dinv*t + bias) ; else: out = dinv * t
template <int F, bool L1>
__global__ void gather_kernel(const float* __restrict__ g, const float* __restrict__ dinv,
                              const int* __restrict__ C, const unsigned* __restrict__ edata,
                              const float* __restrict__ bias, float* __restrict__ out, int n) {
    constexpr int C4 = F / 4;
    int i = blockIdx.x * blockDim.x + threadIdx.x;
    if (i >= n) return;
    int beg = C[i], end = C[i + 1];
    float4 acc[C4];
    const float4* gi = reinterpret_cast<const float4*>(g + (size_t)i * F);
#pragma unroll
    for (int j = 0; j < C4; ++j) acc[j] = gi[j];
    for (int k = beg; k < end; ++k) {
        unsigned v = edata[k];
        int s = (int)(v & 0x3FFFFu);
        float w = (float)(v >> 18) * QINV;
        const float4* gs = reinterpret_cast<const float4*>(g + (size_t)s * F);
#pragma unroll
        for (int j = 0; j < C4; ++j) {
            float4 t = gs[j];
            acc[j].x = fmaf(t.x, w, acc[j].x);
            acc[j].y = fmaf(t.y, w, acc[j].y);
            acc[j].z = fmaf(t.z, w, acc[j].z);
            acc[j].w = fmaf(t.w, w, acc[j].w);
        }
    }
    float dv = dinv[i];
    float4* op = reinterpret_cast<float4*>(out + (size_t)i * F);
#pragma unroll
    for (int j = 0; j < C4; ++j) {
        if (L1) {
            acc[j].x = dv * fmaxf(dv * acc[j].x + bias[j * 4 + 0], 0.0f);
            acc[j].y = dv * fmaxf(dv * acc[j].y + bias[j * 4 + 1], 0.0f);
            acc[j].z = dv * fmaxf(dv * acc[j].z + bias[j * 4 + 2], 0.0f);
            acc[j].w = dv * fmaxf(dv * acc[j].w + bias[j * 4 + 3], 0.0f);
        } else {
            acc[j].x *= dv; acc[j].y *= dv; acc[j].z *= dv; acc[j].w *= dv;
        }
        op[j] = acc[j];
    }
}

// ---- dense + relu + dinv: out = dinv (.) relu(raw @ W + b)
template <int IN, int OUT>
__global__ void dense_kernel(const float* __restrict__ raw, const float* __restrict__ W,
                             const float* __restrict__ b, const float* __restrict__ dinv,
                             float* __restrict__ out, int n) {
    __shared__ float Ws[IN * OUT];
    __shared__ float bs[OUT];
    for (int k = threadIdx.x; k < IN * OUT; k += blockDim.x) Ws[k] = W[k];
    if (threadIdx.x < OUT) bs[threadIdx.x] = b[threadIdx.x];
    __syncthreads();
    int i = blockIdx.x * blockDim.x + threadIdx.x;
    if (i >= n) return;
    float xi[IN];
#pragma unroll
    for (int c = 0; c < IN / 4; ++c) {
        float4 v = *reinterpret_cast<const float4*>(raw + (size_t)i * IN + c * 4);
        xi[c * 4 + 0] = v.x; xi[c * 4 + 1] = v.y; xi[c * 4 + 2] = v.z; xi[c * 4 + 3] = v.w;
    }
    float dv = dinv[i];
#pragma unroll
    for (int o = 0; o < OUT; ++o) {
        float acc = bs[o];
#pragma unroll
        for (int k = 0; k < IN; ++k) acc = fmaf(xi[k], Ws[k * OUT + o], acc);
        out[(size_t)i * OUT + o] = dv * fmaxf(acc, 0.0f);
    }
}

// ---- layer-3 dense + head projection (wf = Wl1@Wl2 fused in-block; h3 never stored)
__global__ void dense3_kernel(const float* __restrict__ raw, const float* __restrict__ W,
                              const float* __restrict__ b, const float* __restrict__ Wl1,
                              const float* __restrict__ bl1, const float* __restrict__ Wl2,
                              const float* __restrict__ bl2, float* __restrict__ pq, int n) {
    __shared__ float Ws[512];
    __shared__ float bs[32];
    __shared__ float wfs[192];
    __shared__ float bfs[3];
    for (int k = threadIdx.x; k < 512; k += blockDim.x) Ws[k] = W[k];
    if (threadIdx.x < 32) bs[threadIdx.x] = b[threadIdx.x];
    if (threadIdx.x < 192) {
        int f = threadIdx.x / 3, j = threadIdx.x % 3;
        float acc = 0.0f;
#pragma unroll
        for (int k = 0; k < 4; ++k) acc = fmaf(Wl1[f * 4 + k], Wl2[k * 3 + j], acc);
        wfs[threadIdx.x] = acc;
    }
    if (threadIdx.x < 3) {
        float acc = bl2[threadIdx.x];
#pragma unroll
        for (int k = 0; k < 4; ++k) acc = fmaf(bl1[k], Wl2[k * 3 + threadIdx.x], acc);
        bfs[threadIdx.x] = acc;
    }
    __syncthreads();
    int i = blockIdx.x * blockDim.x + threadIdx.x;
    if (i >= n) return;
    float xi[16];
#pragma unroll
    for (int c = 0; c < 4; ++c) {
        float4 v = *reinterpret_cast<const float4*>(raw + (size_t)i * 16 + c * 4);
        xi[c * 4 + 0] = v.x; xi[c * 4 + 1] = v.y; xi[c * 4 + 2] = v.z; xi[c * 4 + 3] = v.w;
    }
    float p0 = bfs[0], p1 = bfs[1], p2 = bfs[2];
    float q0 = 0.0f, q1 = 0.0f, q2 = 0.0f;
#pragma unroll
    for (int o = 0; o < 32; ++o) {
        float h = bs[o];
#pragma unroll
        for (int k = 0; k < 16; ++k) h = fmaf(xi[k], Ws[k * 32 + o], h);
        h = fmaxf(h, 0.0f);
        p0 = fmaf(h, wfs[o * 3 + 0], p0);
        p1 = fmaf(h, wfs[o * 3 + 1], p1);
        p2 = fmaf(h, wfs[o * 3 + 2], p2);
        q0 = fmaf(h, wfs[(32 + o) * 3 + 0], q0);
        q1 = fmaf(h, wfs[(32 + o) * 3 + 1], q1);
        q2 = fmaf(h, wfs[(32 + o) * 3 + 2], q2);
    }
    float4 P = {p0, p1, p2, 0.0f};
    float4 Q = {q0, q1, q2, 0.0f};
    *reinterpret_cast<float4*>(pq + (size_t)i * 8 + 0) = P;
    *reinterpret_cast<float4*>(pq + (size_t)i * 8 + 4) = Q;
}

// ---- head: out[e] = p[a] + q[b]
__global__ void head_kernel(const int* __restrict__ w2b, const float4* __restrict__ pq,
                            float* __restrict__ out, int nw) {
    int e = blockIdx.x * blockDim.x + threadIdx.x;
    if (e >= nw) return;
    int a = w2b[e];
    int b = w2b[(size_t)nw + e];
    float4 P = pq[(size_t)a * 2 + 0];
    float4 Q = pq[(size_t)b * 2 + 1];
    out[(size_t)e * 3 + 0] = P.x + Q.x;
    out[(size_t)e * 3 + 1] = P.y + Q.y;
    out[(size_t)e * 3 + 2] = P.z + Q.z;
}

extern "C" void kernel_launch(void* const* d_in, const int* in_sizes, int n_in,
                              void* d_out, int out_size, void* d_ws, size_t ws_size,
                              hipStream_t stream) {
    const float* x   = (const float*)d_in[0];
    const int* eidx  = (const int*)d_in[1];
    const int* w2b   = (const int*)d_in[2];
    const float* ew  = (const float*)d_in[3];
    const float* W1  = (const float*)d_in[4];
    const float* b1  = (const float*)d_in[5];
    const float* W2  = (const float*)d_in[6];
    const float* b2  = (const float*)d_in[7];
    const float* W3  = (const float*)d_in[8];
    const float* b3  = (const float*)d_in[9];
    const float* Wl1 = (const float*)d_in[10];
    const float* bl1 = (const float*)d_in[11];
    const float* Wl2 = (const float*)d_in[12];
    const float* bl2 = (const float*)d_in[13];
    float* out = (float*)d_out;

    const int n  = in_sizes[0] / 7;   // 200000
    const int ne = in_sizes[1] / 2;   // 4000000
    const int nw = in_sizes[2] / 2;   // 2000000
    const int* src = eidx;
    const int* dst = eidx + ne;

    const int nbins = (n + NPB - 1) / NPB;      // 782
    const int chunk = (ne + NB1 - 1) / NB1;     // 15625

    // ---- workspace layout (4B words) ----
    float*         ws      = (float*)d_ws;
    float*         dinv    = ws;                                   // n
    int*           C       = (int*)(ws + n);                       // n+1 (+pad 15)
    unsigned*      edata   = (unsigned*)(ws + 2 * (size_t)n + 16); // ne
    unsigned*      blo     = edata + ne;                           // ne
    unsigned char* bdl     = (unsigned char*)(blo + ne);           // ne bytes
    int*           bh      = (int*)(blo + ne + (ne + 3) / 4);      // nbins*NB1
    int*           bintot  = bh + (size_t)nbins * NB1;             // MAXBINS
    int*           binbase = bintot + MAXBINS;                     // nbins+1 (+pad)
    float*         A       = (float*)(binbase + MAXBINS);          // 16n
    float*         B_      = A + (size_t)n * 16;                   // 16n
    float*         pq      = B_ + (size_t)n * 16;                  // 8n
    // total ~= 41n + 2.25ne + nbins*256 + ~2K words ~= 70.5 MB

    const int Bl = 256;
    auto blks = [&](long long t) { return (int)((t + Bl - 1) / Bl); };
    const int nb = blks(n);  // 782

    // 1. CSR build (counting sort, LDS-aggregated)
    p1a_hist<<<NB1, Bl, 0, stream>>>(dst, bh, ne, nbins, chunk);
    s1_scan<<<nbins, Bl, 0, stream>>>(bh, bintot);
    s2_scan<<<1, 1024, 0, stream>>>(bintot, binbase, nbins, ne);
    p1b_scatter<<<NB1, Bl, 0, stream>>>(src, dst, ew, bh, binbase, blo, bdl, ne, nbins, chunk);
    p2_build<<<nbins, Bl, 0, stream>>>(blo, bdl, binbase, edata, C, dinv, n, ne, nbins);

    // 2. layer 1: A = g0 ; B = g1
    xw1_kernel<<<nb, Bl, 0, stream>>>(x, W1, dinv, A, n);
    gather_kernel<8, true><<<nb, Bl, 0, stream>>>(A, dinv, C, edata, b1, B_, n);

    // 3. layer 2: A = raw2 ; B = g2
    gather_kernel<8, false><<<nb, Bl, 0, stream>>>(B_, dinv, C, edata, nullptr, A, n);
    dense_kernel<8, 16><<<nb, Bl, 0, stream>>>(A, W2, b2, dinv, B_, n);

    // 4. layer 3: A = raw3 ; pq = dense3 + head projection
    gather_kernel<16, false><<<nb, Bl, 0, stream>>>(B_, dinv, C, edata, nullptr, A, n);
    dense3_kernel<<<nb, Bl, 0, stream>>>(A, W3, b3, Wl1, bl1, Wl2, bl2, pq, n);

    // 5. head
    head_kernel<<<blks(nw), Bl, 0, stream>>>(w2b, (const float4*)pq, out, nw);
}

// Round 7
// 550.580 us; speedup vs baseline: 1.4988x; 1.1751x over previous
//
#include <hip/hip_runtime.h>
#include <hip/hip_bf16.h>

// GCN 3-layer + edge-MLP head. R7: counting-sort CSR build where the binning
// scatter (p1b) tile-sorts edges in LDS and flushes bin-contiguous runs
// (write-combined ~42B runs instead of scattered 4B writes). 768 blocks.
//
// Build: bin = dst>>8 (256 nodes/bin). P1a: per-(bin,block) LDS histogram.
// S1/S2: scans -> per-(bin,block) offsets + bin bases. P1b: LDS tile-sort +
// coalesced flush of packed u64 (src|q<<18|dl<<32|bin<<40). P2: one block per
// bin -> node-sorted edata + C + dinv (LDS counters only).
//
// Algebra (verified R4-R6): g = dinv (.) h ; raw_i = dinv_i*(g_i + sum sig*g_src)
// head: out[e] = p[a] + q[b]; p,q fused into layer-3 dense epilogue.

#define NB1 768          // phase-1 blocks (= 3*256 for s1 scan)
#define NPB 256          // nodes per bin
#define MAXBINS 1024     // >= nbins = 782
#define TILE 4096        // edges per LDS sort tile
#define QS 16384.0f
#define QINV (1.0f / 16384.0f)

__device__ __forceinline__ float sigmoidf_(float x) {
    return 1.0f / (1.0f + __expf(-x));
}

// ---- P1a: per-(bin,block) histogram via LDS
__global__ void p1a_hist(const int* __restrict__ dst, int* __restrict__ bh,
                         int ne, int nbins, int chunk) {
    __shared__ int h[MAXBINS];
    for (int k = threadIdx.x; k < nbins; k += 256) h[k] = 0;
    __syncthreads();
    int base = blockIdx.x * chunk;
    int end = min(base + chunk, ne);
    for (int e = base + threadIdx.x; e < end; e += 256)
        atomicAdd(&h[dst[e] >> 8], 1);
    __syncthreads();
    for (int k = threadIdx.x; k < nbins; k += 256)
        bh[(size_t)k * NB1 + blockIdx.x] = h[k];
}

// ---- S1: per-bin exclusive scan over NB1 block counts (in-place) + bin totals
__global__ void s1_scan(int* __restrict__ bh, int* __restrict__ bintot) {
    __shared__ int sums[256];
    constexpr int W = NB1 / 256;
    int* row = bh + (size_t)blockIdx.x * NB1;
    int v[W];
    int s = 0;
#pragma unroll
    for (int j = 0; j < W; ++j) { v[j] = row[threadIdx.x * W + j]; s += v[j]; }
    sums[threadIdx.x] = s;
    __syncthreads();
    for (int o = 1; o < 256; o <<= 1) {
        int t = (threadIdx.x >= o) ? sums[threadIdx.x - o] : 0;
        __syncthreads();
        sums[threadIdx.x] += t;
        __syncthreads();
    }
    int excl = sums[threadIdx.x] - s;
#pragma unroll
    for (int j = 0; j < W; ++j) { row[threadIdx.x * W + j] = excl; excl += v[j]; }
    if (threadIdx.x == 255) bintot[blockIdx.x] = sums[255];
}

// ---- S2: exclusive scan of bin totals -> binbase; binbase[nbins] = ne
__global__ void s2_scan(const int* __restrict__ bintot, int* __restrict__ binbase,
                        int nbins, int ne) {
    __shared__ int tmp[1024];
    int tid = threadIdx.x;
    int v = (tid < nbins) ? bintot[tid] : 0;
    tmp[tid] = v;
    __syncthreads();
    for (int o = 1; o < 1024; o <<= 1) {
        int t = (tid >= o) ? tmp[tid - o] : 0;
        __syncthreads();
        tmp[tid] += t;
        __syncthreads();
    }
    if (tid < nbins) binbase[tid] = tmp[tid] - v;
    if (tid == 0) binbase[nbins] = ne;
}

// ---- P1b: LDS tile-sort + coalesced flush into bin-grouped u64 array
__global__ void p1b_scatter(const int* __restrict__ src, const int* __restrict__ dst,
                            const float* __restrict__ ew, const int* __restrict__ bh,
                            const int* __restrict__ binbase,
                            unsigned long long* __restrict__ b64,
                            int ne, int nbins, int chunk) {
    __shared__ unsigned long long stage[TILE];
    __shared__ int hist[MAXBINS];
    __shared__ int boff[MAXBINS];
    __shared__ int cur[MAXBINS];
    __shared__ int ssum[256];
    constexpr int MPT = TILE / 256;  // max edges per thread per tile
    for (int k = threadIdx.x; k < nbins; k += 256)
        cur[k] = binbase[k] + bh[(size_t)k * NB1 + blockIdx.x];
    int base = blockIdx.x * chunk;
    int endb = min(base + chunk, ne);
    for (int t0 = base; t0 < endb; t0 += TILE) {
        int cnt = min(TILE, endb - t0);
        for (int k = threadIdx.x; k < nbins; k += 256) hist[k] = 0;
        __syncthreads();
        // load + per-tile histogram (entries kept in registers)
        unsigned long long ent[MPT];
        int m = 0;
        for (int j = threadIdx.x; j < cnt; j += 256) {
            int e = t0 + j;
            int d = dst[e];
            float w = sigmoidf_(ew[e]);
            int q = (int)fminf(w * QS + 0.5f, 16383.0f);
            int b = d >> 8;
            ent[m++] = (unsigned long long)((unsigned)src[e] | ((unsigned)q << 18))
                     | ((unsigned long long)(d & 255) << 32)
                     | ((unsigned long long)b << 40);
            atomicAdd(&hist[b], 1);
        }
        __syncthreads();
        // scan hist -> boff (4 bins per thread)
        int w0 = threadIdx.x * 4;
        int lv[4];
        int ls = 0;
#pragma unroll
        for (int j = 0; j < 4; ++j) {
            int idx = w0 + j;
            lv[j] = (idx < nbins) ? hist[idx] : 0;
            ls += lv[j];
        }
        ssum[threadIdx.x] = ls;
        __syncthreads();
        for (int o = 1; o < 256; o <<= 1) {
            int t = (threadIdx.x >= o) ? ssum[threadIdx.x - o] : 0;
            __syncthreads();
            ssum[threadIdx.x] += t;
            __syncthreads();
        }
        int excl = ssum[threadIdx.x] - ls;
#pragma unroll
        for (int j = 0; j < 4; ++j) {
            int idx = w0 + j;
            if (idx < nbins) { boff[idx] = excl; excl += lv[j]; }
        }
        __syncthreads();
        for (int k = threadIdx.x; k < nbins; k += 256) hist[k] = 0;
        __syncthreads();
        // place into LDS stage, bin-sorted
        for (int j = 0; j < m; ++j) {
            int b = (int)(ent[j] >> 40);
            int p = boff[b] + atomicAdd(&hist[b], 1);
            stage[p] = ent[j];
        }
        __syncthreads();
        // coalesced flush: consecutive stage entries share bins -> run writes
        for (int j = threadIdx.x; j < cnt; j += 256) {
            unsigned long long v = stage[j];
            int b = (int)(v >> 40);
            b64[cur[b] + (j - boff[b])] = v;
        }
        __syncthreads();
        // advance run cursors
        for (int k = threadIdx.x; k < nbins; k += 256) cur[k] += hist[k];
        __syncthreads();
    }
}

// ---- P2: per-bin CSR finalize (LDS counters/scan/cursors; no global atomics)
__global__ void p2_build(const unsigned long long* __restrict__ b64,
                         const int* __restrict__ binbase, unsigned* __restrict__ edata,
                         int* __restrict__ C, float* __restrict__ dinv,
                         int n, int ne, int nbins) {
    __shared__ int cnt[NPB];
    __shared__ int rs[NPB];
    __shared__ int curs[NPB];
    __shared__ unsigned qsum[NPB];
    int b = blockIdx.x;
    int E0 = binbase[b], E1 = binbase[b + 1];
    cnt[threadIdx.x] = 0;
    qsum[threadIdx.x] = 0;
    __syncthreads();
    for (int k = E0 + threadIdx.x; k < E1; k += 256)
        atomicAdd(&cnt[(int)((b64[k] >> 32) & 0xFF)], 1);
    __syncthreads();
    int v = cnt[threadIdx.x];
    rs[threadIdx.x] = v;
    __syncthreads();
    for (int o = 1; o < NPB; o <<= 1) {
        int t = (threadIdx.x >= o) ? rs[threadIdx.x - o] : 0;
        __syncthreads();
        rs[threadIdx.x] += t;
        __syncthreads();
    }
    int excl = rs[threadIdx.x] - v;
    curs[threadIdx.x] = E0 + excl;
    int node = b * NPB + threadIdx.x;
    if (node < n) C[node] = E0 + excl;
    if (b == 0 && threadIdx.x == 0) C[n] = ne;
    __syncthreads();
    for (int k = E0 + threadIdx.x; k < E1; k += 256) {
        unsigned long long e64 = b64[k];
        int dl = (int)((e64 >> 32) & 0xFF);
        int pos = atomicAdd(&curs[dl], 1);
        edata[pos] = (unsigned)(e64 & 0xFFFFFFFFu);
        atomicAdd(&qsum[dl], (unsigned)((e64 >> 18) & 0x3FFFu));
    }
    __syncthreads();
    if (node < n) dinv[node] = rsqrtf((float)qsum[threadIdx.x] * QINV + 1.0f);
}

// ---- layer-1 pre-transform: g0 = dinv (.) (x @ W1)   (7 -> 8)
__global__ void xw1_kernel(const float* __restrict__ x, const float* __restrict__ W,
                           const float* __restrict__ dinv, float* __restrict__ g, int n) {
    __shared__ float Ws[56];
    if (threadIdx.x < 56) Ws[threadIdx.x] = W[threadIdx.x];
    __syncthreads();
    int i = blockIdx.x * blockDim.x + threadIdx.x;
    if (i >= n) return;
    float xi[7];
#pragma unroll
    for (int k = 0; k < 7; ++k) xi[k] = x[(size_t)i * 7 + k];
    float dv = dinv[i];
#pragma unroll
    for (int o = 0; o < 8; ++o) {
        float acc = 0.0f;
#pragma unroll
        for (int k = 0; k < 7; ++k) acc = fmaf(xi[k], Ws[k * 8 + o], acc);
        g[(size_t)i * 8 + o] = acc * dv;
    }
}

// ---- thread-per-node gather-reduce: t = g[i] + sum sig*g[src]
template <int F, bool L1>
__global__ void gather_kernel(const float* __restrict__ g, const float* __restrict__ dinv,
                              const int* __restrict__ C, const unsigned* __restrict__ edata,
                              const float* __restrict__ bias, float* __restrict__ out, int n) {
    constexpr int C4 = F / 4;
    int i = blockIdx.x * blockDim.x + threadIdx.x;
    if (i >= n) return;
    int beg = C[i], end = C[i + 1];
    float4 acc[C4];
    const float4* gi = reinterpret_cast<const float4*>(g + (size_t)i * F);
#pragma unroll
    for (int j = 0; j < C4; ++j) acc[j] = gi[j];
    for (int k = beg; k < end; ++k) {
        unsigned v = edata[k];
        int s = (int)(v & 0x3FFFFu);
        float w = (float)(v >> 18) * QINV;
        const float4* gs = reinterpret_cast<const float4*>(g + (size_t)s * F);
#pragma unroll
        for (int j = 0; j < C4; ++j) {
            float4 t = gs[j];
            acc[j].x = fmaf(t.x, w, acc[j].x);
            acc[j].y = fmaf(t.y, w, acc[j].y);
            acc[j].z = fmaf(t.z, w, acc[j].z);
            acc[j].w = fmaf(t.w, w, acc[j].w);
        }
    }
    float dv = dinv[i];
    float4* op = reinterpret_cast<float4*>(out + (size_t)i * F);
#pragma unroll
    for (int j = 0; j < C4; ++j) {
        if (L1) {
            acc[j].x = dv * fmaxf(dv * acc[j].x + bias[j * 4 + 0], 0.0f);
            acc[j].y = dv * fmaxf(dv * acc[j].y + bias[j * 4 + 1], 0.0f);
            acc[j].z = dv * fmaxf(dv * acc[j].z + bias[j * 4 + 2], 0.0f);
            acc[j].w = dv * fmaxf(dv * acc[j].w + bias[j * 4 + 3], 0.0f);
        } else {
            acc[j].x *= dv; acc[j].y *= dv; acc[j].z *= dv; acc[j].w *= dv;
        }
        op[j] = acc[j];
    }
}

// ---- dense + relu + dinv: out = dinv (.) relu(raw @ W + b)
template <int IN, int OUT>
__global__ void dense_kernel(const float* __restrict__ raw, const float* __restrict__ W,
                             const float* __restrict__ b, const float* __restrict__ dinv,
                             float* __restrict__ out, int n) {
    __shared__ float Ws[IN * OUT];
    __shared__ float bs[OUT];
    for (int k = threadIdx.x; k < IN * OUT; k += blockDim.x) Ws[k] = W[k];
    if (threadIdx.x < OUT) bs[threadIdx.x] = b[threadIdx.x];
    __syncthreads();
    int i = blockIdx.x * blockDim.x + threadIdx.x;
    if (i >= n) return;
    float xi[IN];
#pragma unroll
    for (int c = 0; c < IN / 4; ++c) {
        float4 v = *reinterpret_cast<const float4*>(raw + (size_t)i * IN + c * 4);
        xi[c * 4 + 0] = v.x; xi[c * 4 + 1] = v.y; xi[c * 4 + 2] = v.z; xi[c * 4 + 3] = v.w;
    }
    float dv = dinv[i];
#pragma unroll
    for (int o = 0; o < OUT; ++o) {
        float acc = bs[o];
#pragma unroll
        for (int k = 0; k < IN; ++k) acc = fmaf(xi[k], Ws[k * OUT + o], acc);
        out[(size_t)i * OUT + o] = dv * fmaxf(acc, 0.0f);
    }
}

// ---- layer-3 dense + head projection (wf = Wl1@Wl2 fused in-block)
__global__ void dense3_kernel(const float* __restrict__ raw, const float* __restrict__ W,
                              const float* __restrict__ b, const float* __restrict__ Wl1,
                              const float* __restrict__ bl1, const float* __restrict__ Wl2,
                              const float* __restrict__ bl2, float* __restrict__ pq, int n) {
    __shared__ float Ws[512];
    __shared__ float bs[32];
    __shared__ float wfs[192];
    __shared__ float bfs[3];
    for (int k = threadIdx.x; k < 512; k += blockDim.x) Ws[k] = W[k];
    if (threadIdx.x < 32) bs[threadIdx.x] = b[threadIdx.x];
    if (threadIdx.x < 192) {
        int f = threadIdx.x / 3, j = threadIdx.x % 3;
        float acc = 0.0f;
#pragma unroll
        for (int k = 0; k < 4; ++k) acc = fmaf(Wl1[f * 4 + k], Wl2[k * 3 + j], acc);
        wfs[threadIdx.x] = acc;
    }
    if (threadIdx.x < 3) {
        float acc = bl2[threadIdx.x];
#pragma unroll
        for (int k = 0; k < 4; ++k) acc = fmaf(bl1[k], Wl2[k * 3 + threadIdx.x], acc);
        bfs[threadIdx.x] = acc;
    }
    __syncthreads();
    int i = blockIdx.x * blockDim.x + threadIdx.x;
    if (i >= n) return;
    float xi[16];
#pragma unroll
    for (int c = 0; c < 4; ++c) {
        float4 v = *reinterpret_cast<const float4*>(raw + (size_t)i * 16 + c * 4);
        xi[c * 4 + 0] = v.x; xi[c * 4 + 1] = v.y; xi[c * 4 + 2] = v.z; xi[c * 4 + 3] = v.w;
    }
    float p0 = bfs[0], p1 = bfs[1], p2 = bfs[2];
    float q0 = 0.0f, q1 = 0.0f, q2 = 0.0f;
#pragma unroll
    for (int o = 0; o < 32; ++o) {
        float h = bs[o];
#pragma unroll
        for (int k = 0; k < 16; ++k) h = fmaf(xi[k], Ws[k * 32 + o], h);
        h = fmaxf(h, 0.0f);
        p0 = fmaf(h, wfs[o * 3 + 0], p0);
        p1 = fmaf(h, wfs[o * 3 + 1], p1);
        p2 = fmaf(h, wfs[o * 3 + 2], p2);
        q0 = fmaf(h, wfs[(32 + o) * 3 + 0], q0);
        q1 = fmaf(h, wfs[(32 + o) * 3 + 1], q1);
        q2 = fmaf(h, wfs[(32 + o) * 3 + 2], q2);
    }
    float4 P = {p0, p1, p2, 0.0f};
    float4 Q = {q0, q1, q2, 0.0f};
    *reinterpret_cast<float4*>(pq + (size_t)i * 8 + 0) = P;
    *reinterpret_cast<float4*>(pq + (size_t)i * 8 + 4) = Q;
}

// ---- head: out[e] = p[a] + q[b]
__global__ void head_kernel(const int* __restrict__ w2b, const float4* __restrict__ pq,
                            float* __restrict__ out, int nw) {
    int e = blockIdx.x * blockDim.x + threadIdx.x;
    if (e >= nw) return;
    int a = w2b[e];
    int b = w2b[(size_t)nw + e];
    float4 P = pq[(size_t)a * 2 + 0];
    float4 Q = pq[(size_t)b * 2 + 1];
    out[(size_t)e * 3 + 0] = P.x + Q.x;
    out[(size_t)e * 3 + 1] = P.y + Q.y;
    out[(size_t)e * 3 + 2] = P.z + Q.z;
}

extern "C" void kernel_launch(void* const* d_in, const int* in_sizes, int n_in,
                              void* d_out, int out_size, void* d_ws, size_t ws_size,
                              hipStream_t stream) {
    const float* x   = (const float*)d_in[0];
    const int* eidx  = (const int*)d_in[1];
    const int* w2b   = (const int*)d_in[2];
    const float* ew  = (const float*)d_in[3];
    const float* W1  = (const float*)d_in[4];
    const float* b1  = (const float*)d_in[5];
    const float* W2  = (const float*)d_in[6];
    const float* b2  = (const float*)d_in[7];
    const float* W3  = (const float*)d_in[8];
    const float* b3  = (const float*)d_in[9];
    const float* Wl1 = (const float*)d_in[10];
    const float* bl1 = (const float*)d_in[11];
    const float* Wl2 = (const float*)d_in[12];
    const float* bl2 = (const float*)d_in[13];
    float* out = (float*)d_out;

    const int n  = in_sizes[0] / 7;   // 200000
    const int ne = in_sizes[1] / 2;   // 4000000
    const int nw = in_sizes[2] / 2;   // 2000000
    const int* src = eidx;
    const int* dst = eidx + ne;

    const int nbins = (n + NPB - 1) / NPB;      // 782
    const int chunk = (ne + NB1 - 1) / NB1;     // 5209

    // ---- workspace layout (4B words); b64 aliases the A/B/pq region ----
    float*    ws      = (float*)d_ws;
    float*    dinv    = ws;                                    // n
    int*      C       = (int*)(ws + n);                        // n+1 (+pad)
    unsigned* edata   = (unsigned*)(ws + 2 * (size_t)n + 16);  // ne
    int*      bh      = (int*)(edata + ne);                    // nbins*NB1
    int*      bintot  = bh + (size_t)nbins * NB1;              // MAXBINS
    int*      binbase = bintot + MAXBINS;                      // MAXBINS
    float*    A       = (float*)(binbase + MAXBINS);           // 16n  } union with
    float*    B_      = A + (size_t)n * 16;                    // 16n  } b64 (ne u64)
    float*    pq      = B_ + (size_t)n * 16;                   // 8n   }
    unsigned long long* b64 = (unsigned long long*)A;          // dead after p2
    // total ~= 2n+16 + ne + nbins*NB1 + 2048 + max(2*ne, 40n) words ~= 59 MB

    const int Bl = 256;
    auto blks = [&](long long t) { return (int)((t + Bl - 1) / Bl); };
    const int nb = blks(n);  // 782

    // 1. CSR build (counting sort; tile-sorted write-combined scatter)
    p1a_hist<<<NB1, Bl, 0, stream>>>(dst, bh, ne, nbins, chunk);
    s1_scan<<<nbins, Bl, 0, stream>>>(bh, bintot);
    s2_scan<<<1, 1024, 0, stream>>>(bintot, binbase, nbins, ne);
    p1b_scatter<<<NB1, Bl, 0, stream>>>(src, dst, ew, bh, binbase, b64, ne, nbins, chunk);
    p2_build<<<nbins, Bl, 0, stream>>>(b64, binbase, edata, C, dinv, n, ne, nbins);

    // 2. layer 1: A = g0 ; B = g1
    xw1_kernel<<<nb, Bl, 0, stream>>>(x, W1, dinv, A, n);
    gather_kernel<8, true><<<nb, Bl, 0, stream>>>(A, dinv, C, edata, b1, B_, n);

    // 3. layer 2: A = raw2 ; B = g2
    gather_kernel<8, false><<<nb, Bl, 0, stream>>>(B_, dinv, C, edata, nullptr, A, n);
    dense_kernel<8, 16><<<nb, Bl, 0, stream>>>(A, W2, b2, dinv, B_, n);

    // 4. layer 3: A = raw3 ; pq = dense3 + head projection
    gather_kernel<16, false><<<nb, Bl, 0, stream>>>(B_, dinv, C, edata, nullptr, A, n);
    dense3_kernel<<<nb, Bl, 0, stream>>>(A, W3, b3, Wl1, bl1, Wl2, bl2, pq, n);

    // 5. head
    head_kernel<<<blks(nw), Bl, 0, stream>>>(w2b, (const float4*)pq, out, nw);
}

// Round 8
// 452.023 us; speedup vs baseline: 1.8255x; 1.2180x over previous
//
#include <hip/hip_runtime.h>
#include <hip/hip_bf16.h>
#include <hip/hip_fp16.h>

// GCN 3-layer + edge-MLP head. R8: fp16 feature tables (L2-resident gathers,
// fp32 accumulation) + all dense transforms fused into gather epilogues.
//
// Build (R7, unchanged): bin = dst>>8. p1a per-(bin,block) LDS histogram;
// s1/s2 scans; p1b LDS tile-sort + write-combined flush of u64
// (src|q<<18|dl<<32|bin<<40); p2 per-bin CSR finalize + dinv + fused g0=dinv(.)(x@W1).
//
// Layers: g=dinv(.)h fp16; raw_i=dinv_i*(g_i+sum sig*g_src) fp32.
// gather1: ->g1 (relu+bias epilogue). gather2: +dense 8->16 -> g2.
// gather3: +dense 16->32 + head projection -> pq (fp32).
// head: out[e] = p[a] + q[b].

#define NB1 768
#define NPB 256
#define MAXBINS 1024
#define TILE 4096
#define QS 16384.0f
#define QINV (1.0f / 16384.0f)

typedef _Float16 h8 __attribute__((ext_vector_type(8)));
typedef _Float16 h16 __attribute__((ext_vector_type(16)));

__device__ __forceinline__ float sigmoidf_(float x) {
    return 1.0f / (1.0f + __expf(-x));
}

// ---- P1a: per-(bin,block) histogram via LDS
__global__ void p1a_hist(const int* __restrict__ dst, int* __restrict__ bh,
                         int ne, int nbins, int chunk) {
    __shared__ int h[MAXBINS];
    for (int k = threadIdx.x; k < nbins; k += 256) h[k] = 0;
    __syncthreads();
    int base = blockIdx.x * chunk;
    int end = min(base + chunk, ne);
    for (int e = base + threadIdx.x; e < end; e += 256)
        atomicAdd(&h[dst[e] >> 8], 1);
    __syncthreads();
    for (int k = threadIdx.x; k < nbins; k += 256)
        bh[(size_t)k * NB1 + blockIdx.x] = h[k];
}

// ---- S1: per-bin exclusive scan over NB1 block counts + bin totals
__global__ void s1_scan(int* __restrict__ bh, int* __restrict__ bintot) {
    __shared__ int sums[256];
    constexpr int W = NB1 / 256;
    int* row = bh + (size_t)blockIdx.x * NB1;
    int v[W];
    int s = 0;
#pragma unroll
    for (int j = 0; j < W; ++j) { v[j] = row[threadIdx.x * W + j]; s += v[j]; }
    sums[threadIdx.x] = s;
    __syncthreads();
    for (int o = 1; o < 256; o <<= 1) {
        int t = (threadIdx.x >= o) ? sums[threadIdx.x - o] : 0;
        __syncthreads();
        sums[threadIdx.x] += t;
        __syncthreads();
    }
    int excl = sums[threadIdx.x] - s;
#pragma unroll
    for (int j = 0; j < W; ++j) { row[threadIdx.x * W + j] = excl; excl += v[j]; }
    if (threadIdx.x == 255) bintot[blockIdx.x] = sums[255];
}

// ---- S2: exclusive scan of bin totals -> binbase
__global__ void s2_scan(const int* __restrict__ bintot, int* __restrict__ binbase,
                        int nbins, int ne) {
    __shared__ int tmp[1024];
    int tid = threadIdx.x;
    int v = (tid < nbins) ? bintot[tid] : 0;
    tmp[tid] = v;
    __syncthreads();
    for (int o = 1; o < 1024; o <<= 1) {
        int t = (tid >= o) ? tmp[tid - o] : 0;
        __syncthreads();
        tmp[tid] += t;
        __syncthreads();
    }
    if (tid < nbins) binbase[tid] = tmp[tid] - v;
    if (tid == 0) binbase[nbins] = ne;
}

// ---- P1b: LDS tile-sort + coalesced flush into bin-grouped u64 array
__global__ void p1b_scatter(const int* __restrict__ src, const int* __restrict__ dst,
                            const float* __restrict__ ew, const int* __restrict__ bh,
                            const int* __restrict__ binbase,
                            unsigned long long* __restrict__ b64,
                            int ne, int nbins, int chunk) {
    __shared__ unsigned long long stage[TILE];
    __shared__ int hist[MAXBINS];
    __shared__ int boff[MAXBINS];
    __shared__ int cur[MAXBINS];
    __shared__ int ssum[256];
    constexpr int MPT = TILE / 256;
    for (int k = threadIdx.x; k < nbins; k += 256)
        cur[k] = binbase[k] + bh[(size_t)k * NB1 + blockIdx.x];
    int base = blockIdx.x * chunk;
    int endb = min(base + chunk, ne);
    for (int t0 = base; t0 < endb; t0 += TILE) {
        int cnt = min(TILE, endb - t0);
        for (int k = threadIdx.x; k < nbins; k += 256) hist[k] = 0;
        __syncthreads();
        unsigned long long ent[MPT];
        int m = 0;
        for (int j = threadIdx.x; j < cnt; j += 256) {
            int e = t0 + j;
            int d = dst[e];
            float w = sigmoidf_(ew[e]);
            int q = (int)fminf(w * QS + 0.5f, 16383.0f);
            int b = d >> 8;
            ent[m++] = (unsigned long long)((unsigned)src[e] | ((unsigned)q << 18))
                     | ((unsigned long long)(d & 255) << 32)
                     | ((unsigned long long)b << 40);
            atomicAdd(&hist[b], 1);
        }
        __syncthreads();
        int w0 = threadIdx.x * 4;
        int lv[4];
        int ls = 0;
#pragma unroll
        for (int j = 0; j < 4; ++j) {
            int idx = w0 + j;
            lv[j] = (idx < nbins) ? hist[idx] : 0;
            ls += lv[j];
        }
        ssum[threadIdx.x] = ls;
        __syncthreads();
        for (int o = 1; o < 256; o <<= 1) {
            int t = (threadIdx.x >= o) ? ssum[threadIdx.x - o] : 0;
            __syncthreads();
            ssum[threadIdx.x] += t;
            __syncthreads();
        }
        int excl = ssum[threadIdx.x] - ls;
#pragma unroll
        for (int j = 0; j < 4; ++j) {
            int idx = w0 + j;
            if (idx < nbins) { boff[idx] = excl; excl += lv[j]; }
        }
        __syncthreads();
        for (int k = threadIdx.x; k < nbins; k += 256) hist[k] = 0;
        __syncthreads();
        for (int j = 0; j < m; ++j) {
            int b = (int)(ent[j] >> 40);
            int p = boff[b] + atomicAdd(&hist[b], 1);
            stage[p] = ent[j];
        }
        __syncthreads();
        for (int j = threadIdx.x; j < cnt; j += 256) {
            unsigned long long v = stage[j];
            int b = (int)(v >> 40);
            b64[cur[b] + (j - boff[b])] = v;
        }
        __syncthreads();
        for (int k = threadIdx.x; k < nbins; k += 256) cur[k] += hist[k];
        __syncthreads();
    }
}

// ---- P2: per-bin CSR finalize + dinv + FUSED g0 = dinv (.) (x @ W1) in fp16
__global__ void p2_build(const unsigned long long* __restrict__ b64,
                         const int* __restrict__ binbase, unsigned* __restrict__ edata,
                         int* __restrict__ C, float* __restrict__ dinv,
                         const float* __restrict__ x, const float* __restrict__ W1,
                         _Float16* __restrict__ g0, int n, int ne, int nbins) {
    __shared__ int cnt[NPB];
    __shared__ int rs[NPB];
    __shared__ int curs[NPB];
    __shared__ unsigned qsum[NPB];
    __shared__ float Ws[56];
    if (threadIdx.x < 56) Ws[threadIdx.x] = W1[threadIdx.x];
    int b = blockIdx.x;
    int E0 = binbase[b], E1 = binbase[b + 1];
    cnt[threadIdx.x] = 0;
    qsum[threadIdx.x] = 0;
    __syncthreads();
    for (int k = E0 + threadIdx.x; k < E1; k += 256)
        atomicAdd(&cnt[(int)((b64[k] >> 32) & 0xFF)], 1);
    __syncthreads();
    int v = cnt[threadIdx.x];
    rs[threadIdx.x] = v;
    __syncthreads();
    for (int o = 1; o < NPB; o <<= 1) {
        int t = (threadIdx.x >= o) ? rs[threadIdx.x - o] : 0;
        __syncthreads();
        rs[threadIdx.x] += t;
        __syncthreads();
    }
    int excl = rs[threadIdx.x] - v;
    curs[threadIdx.x] = E0 + excl;
    int node = b * NPB + threadIdx.x;
    if (node < n) C[node] = E0 + excl;
    if (b == 0 && threadIdx.x == 0) C[n] = ne;
    __syncthreads();
    for (int k = E0 + threadIdx.x; k < E1; k += 256) {
        unsigned long long e64 = b64[k];
        int dl = (int)((e64 >> 32) & 0xFF);
        int pos = atomicAdd(&curs[dl], 1);
        edata[pos] = (unsigned)(e64 & 0xFFFFFFFFu);
        atomicAdd(&qsum[dl], (unsigned)((e64 >> 18) & 0x3FFFu));
    }
    __syncthreads();
    if (node < n) {
        float dv = rsqrtf((float)qsum[threadIdx.x] * QINV + 1.0f);
        dinv[node] = dv;
        float xi[7];
#pragma unroll
        for (int k = 0; k < 7; ++k) xi[k] = x[(size_t)node * 7 + k];
        h8 r;
#pragma unroll
        for (int o = 0; o < 8; ++o) {
            float acc = 0.0f;
#pragma unroll
            for (int k = 0; k < 7; ++k) acc = fmaf(xi[k], Ws[k * 8 + o], acc);
            r[o] = (_Float16)(acc * dv);
        }
        *reinterpret_cast<h8*>(g0 + (size_t)node * 8) = r;
    }
}

// ---- gather layer 1 (F=8): g1 = dinv * relu(dinv*(g0_i + sum sig*g0_src) + b1)
__global__ void gather1_kernel(const _Float16* __restrict__ g, const float* __restrict__ dinv,
                               const int* __restrict__ C, const unsigned* __restrict__ edata,
                               const float* __restrict__ b1, _Float16* __restrict__ out, int n) {
    __shared__ float bs[8];
    if (threadIdx.x < 8) bs[threadIdx.x] = b1[threadIdx.x];
    __syncthreads();
    int i = blockIdx.x * blockDim.x + threadIdx.x;
    if (i >= n) return;
    int beg = C[i], end = C[i + 1];
    h8 r0 = *reinterpret_cast<const h8*>(g + (size_t)i * 8);
    float acc[8];
#pragma unroll
    for (int j = 0; j < 8; ++j) acc[j] = (float)r0[j];
    for (int k = beg; k < end; ++k) {
        unsigned v = edata[k];
        int s = (int)(v & 0x3FFFFu);
        float w = (float)(v >> 18) * QINV;
        h8 r = *reinterpret_cast<const h8*>(g + (size_t)s * 8);
#pragma unroll
        for (int j = 0; j < 8; ++j) acc[j] = fmaf((float)r[j], w, acc[j]);
    }
    float dv = dinv[i];
    h8 o8;
#pragma unroll
    for (int j = 0; j < 8; ++j)
        o8[j] = (_Float16)(dv * fmaxf(dv * acc[j] + bs[j], 0.0f));
    *reinterpret_cast<h8*>(out + (size_t)i * 8) = o8;
}

// ---- gather layer 2 (F=8) + fused dense 8->16: g2 = dinv * relu(raw2@W2 + b2)
__global__ void gather2_kernel(const _Float16* __restrict__ g, const float* __restrict__ dinv,
                               const int* __restrict__ C, const unsigned* __restrict__ edata,
                               const float* __restrict__ W2, const float* __restrict__ b2,
                               _Float16* __restrict__ out, int n) {
    __shared__ float Ws[128];
    __shared__ float bs[16];
    if (threadIdx.x < 128) Ws[threadIdx.x] = W2[threadIdx.x];
    if (threadIdx.x < 16) bs[threadIdx.x] = b2[threadIdx.x];
    __syncthreads();
    int i = blockIdx.x * blockDim.x + threadIdx.x;
    if (i >= n) return;
    int beg = C[i], end = C[i + 1];
    h8 r0 = *reinterpret_cast<const h8*>(g + (size_t)i * 8);
    float acc[8];
#pragma unroll
    for (int j = 0; j < 8; ++j) acc[j] = (float)r0[j];
    for (int k = beg; k < end; ++k) {
        unsigned v = edata[k];
        int s = (int)(v & 0x3FFFFu);
        float w = (float)(v >> 18) * QINV;
        h8 r = *reinterpret_cast<const h8*>(g + (size_t)s * 8);
#pragma unroll
        for (int j = 0; j < 8; ++j) acc[j] = fmaf((float)r[j], w, acc[j]);
    }
    float dv = dinv[i];
#pragma unroll
    for (int j = 0; j < 8; ++j) acc[j] *= dv;  // raw2
    h16 o16;
#pragma unroll
    for (int o = 0; o < 16; ++o) {
        float h = bs[o];
#pragma unroll
        for (int k = 0; k < 8; ++k) h = fmaf(acc[k], Ws[k * 16 + o], h);
        o16[o] = (_Float16)(dv * fmaxf(h, 0.0f));
    }
    *reinterpret_cast<h16*>(out + (size_t)i * 16) = o16;
}

// ---- gather layer 3 (F=16) + fused dense 16->32 + head projection -> pq (fp32)
__global__ void gather3_kernel(const _Float16* __restrict__ g, const float* __restrict__ dinv,
                               const int* __restrict__ C, const unsigned* __restrict__ edata,
                               const float* __restrict__ W3, const float* __restrict__ b3,
                               const float* __restrict__ Wl1, const float* __restrict__ bl1,
                               const float* __restrict__ Wl2, const float* __restrict__ bl2,
                               float* __restrict__ pq, int n) {
    __shared__ float Ws[512];
    __shared__ float bs[32];
    __shared__ float wfs[192];
    __shared__ float bfs[3];
    for (int k = threadIdx.x; k < 512; k += 256) Ws[k] = W3[k];
    if (threadIdx.x < 32) bs[threadIdx.x] = b3[threadIdx.x];
    if (threadIdx.x < 192) {
        int f = threadIdx.x / 3, j = threadIdx.x % 3;
        float acc = 0.0f;
#pragma unroll
        for (int k = 0; k < 4; ++k) acc = fmaf(Wl1[f * 4 + k], Wl2[k * 3 + j], acc);
        wfs[threadIdx.x] = acc;
    }
    if (threadIdx.x < 3) {
        float acc = bl2[threadIdx.x];
#pragma unroll
        for (int k = 0; k < 4; ++k) acc = fmaf(bl1[k], Wl2[k * 3 + threadIdx.x], acc);
        bfs[threadIdx.x] = acc;
    }
    __syncthreads();
    int i = blockIdx.x * blockDim.x + threadIdx.x;
    if (i >= n) return;
    int beg = C[i], end = C[i + 1];
    h16 r0 = *reinterpret_cast<const h16*>(g + (size_t)i * 16);
    float acc[16];
#pragma unroll
    for (int j = 0; j < 16; ++j) acc[j] = (float)r0[j];
    for (int k = beg; k < end; ++k) {
        unsigned v = edata[k];
        int s = (int)(v & 0x3FFFFu);
        float w = (float)(v >> 18) * QINV;
        h16 r = *reinterpret_cast<const h16*>(g + (size_t)s * 16);
#pragma unroll
        for (int j = 0; j < 16; ++j) acc[j] = fmaf((float)r[j], w, acc[j]);
    }
    float dv = dinv[i];
#pragma unroll
    for (int j = 0; j < 16; ++j) acc[j] *= dv;  // raw3
    float p0 = bfs[0], p1 = bfs[1], p2 = bfs[2];
    float q0 = 0.0f, q1 = 0.0f, q2 = 0.0f;
#pragma unroll
    for (int o = 0; o < 32; ++o) {
        float h = bs[o];
#pragma unroll
        for (int k = 0; k < 16; ++k) h = fmaf(acc[k], Ws[k * 32 + o], h);
        h = fmaxf(h, 0.0f);
        p0 = fmaf(h, wfs[o * 3 + 0], p0);
        p1 = fmaf(h, wfs[o * 3 + 1], p1);
        p2 = fmaf(h, wfs[o * 3 + 2], p2);
        q0 = fmaf(h, wfs[(32 + o) * 3 + 0], q0);
        q1 = fmaf(h, wfs[(32 + o) * 3 + 1], q1);
        q2 = fmaf(h, wfs[(32 + o) * 3 + 2], q2);
    }
    float4 P = {p0, p1, p2, 0.0f};
    float4 Q = {q0, q1, q2, 0.0f};
    *reinterpret_cast<float4*>(pq + (size_t)i * 8 + 0) = P;
    *reinterpret_cast<float4*>(pq + (size_t)i * 8 + 4) = Q;
}

// ---- head: out[e] = p[a] + q[b]
__global__ void head_kernel(const int* __restrict__ w2b, const float4* __restrict__ pq,
                            float* __restrict__ out, int nw) {
    int e = blockIdx.x * blockDim.x + threadIdx.x;
    if (e >= nw) return;
    int a = w2b[e];
    int b = w2b[(size_t)nw + e];
    float4 P = pq[(size_t)a * 2 + 0];
    float4 Q = pq[(size_t)b * 2 + 1];
    out[(size_t)e * 3 + 0] = P.x + Q.x;
    out[(size_t)e * 3 + 1] = P.y + Q.y;
    out[(size_t)e * 3 + 2] = P.z + Q.z;
}

extern "C" void kernel_launch(void* const* d_in, const int* in_sizes, int n_in,
                              void* d_out, int out_size, void* d_ws, size_t ws_size,
                              hipStream_t stream) {
    const float* x   = (const float*)d_in[0];
    const int* eidx  = (const int*)d_in[1];
    const int* w2b   = (const int*)d_in[2];
    const float* ew  = (const float*)d_in[3];
    const float* W1  = (const float*)d_in[4];
    const float* b1  = (const float*)d_in[5];
    const float* W2  = (const float*)d_in[6];
    const float* b2  = (const float*)d_in[7];
    const float* W3  = (const float*)d_in[8];
    const float* b3  = (const float*)d_in[9];
    const float* Wl1 = (const float*)d_in[10];
    const float* bl1 = (const float*)d_in[11];
    const float* Wl2 = (const float*)d_in[12];
    const float* bl2 = (const float*)d_in[13];
    float* out = (float*)d_out;

    const int n  = in_sizes[0] / 7;   // 200000
    const int ne = in_sizes[1] / 2;   // 4000000
    const int nw = in_sizes[2] / 2;   // 2000000
    const int* src = eidx;
    const int* dst = eidx + ne;

    const int nbins = (n + NPB - 1) / NPB;    // 782
    const int chunk = (ne + NB1 - 1) / NB1;   // 5209

    // ---- workspace layout (4B words) ----
    float*     ws      = (float*)d_ws;
    float*     dinv    = ws;                                    // n
    int*       C       = (int*)(ws + n);                        // n+1 (+pad)
    unsigned*  edata   = (unsigned*)(ws + 2 * (size_t)n + 16);  // ne
    int*       bh      = (int*)(edata + ne);                    // nbins*NB1
    int*       bintot  = bh + (size_t)nbins * NB1;              // MAXBINS
    int*       binbase = bintot + MAXBINS;                      // MAXBINS
    _Float16*  g0      = (_Float16*)(binbase + MAXBINS);        // 8n halves (4n words)
    float*     bregion = (float*)(g0 + (size_t)n * 8);          // 2*ne words
    unsigned long long* b64 = (unsigned long long*)bregion;     // ne u64 (dead after p2)
    _Float16*  g1      = (_Float16*)bregion;                    // 8n halves  } alias
    _Float16*  g2      = (_Float16*)(bregion + 4 * (size_t)n);  // 16n halves } into
    float*     pq      = bregion + 12 * (size_t)n;              // 8n floats  } b64
    // total ~= 2n+16+ne+nbins*768+2048+4n+2ne words ~= 55 MB

    const int Bl = 256;
    auto blks = [&](long long t) { return (int)((t + Bl - 1) / Bl); };
    const int nb = blks(n);  // 782

    // 1. CSR build (counting sort; tile-sorted write-combined scatter)
    p1a_hist<<<NB1, Bl, 0, stream>>>(dst, bh, ne, nbins, chunk);
    s1_scan<<<nbins, Bl, 0, stream>>>(bh, bintot);
    s2_scan<<<1, 1024, 0, stream>>>(bintot, binbase, nbins, ne);
    p1b_scatter<<<NB1, Bl, 0, stream>>>(src, dst, ew, bh, binbase, b64, ne, nbins, chunk);
    p2_build<<<nbins, Bl, 0, stream>>>(b64, binbase, edata, C, dinv, x, W1, g0, n, ne, nbins);

    // 2. three fused gather layers
    gather1_kernel<<<nb, Bl, 0, stream>>>(g0, dinv, C, edata, b1, g1, n);
    gather2_kernel<<<nb, Bl, 0, stream>>>(g1, dinv, C, edata, W2, b2, g2, n);
    gather3_kernel<<<nb, Bl, 0, stream>>>(g2, dinv, C, edata, W3, b3,
                                          Wl1, bl1, Wl2, bl2, pq, n);

    // 3. head
    head_kernel<<<blks(nw), Bl, 0, stream>>>(w2b, (const float4*)pq, out, nw);
}

// Round 9
// 409.931 us; speedup vs baseline: 2.0130x; 1.1027x over previous
//
#include <hip/hip_runtime.h>
#include <hip/hip_bf16.h>
#include <hip/hip_fp16.h>

// GCN 3-layer + edge-MLP head. R9: quad-per-node feature-split gathers
// (4 lanes/node, 4x memory-level parallelism, coalesced row reads,
// __shfl_xor to rebuild full vectors for fused dense epilogues) +
// fp16 pq table (3.2MB, L2-resident head gathers).
//
// Build (R7/R8): bin = dst>>8. p1a per-(bin,block) LDS histogram; s1/s2 scans;
// p1b LDS tile-sort + write-combined flush of u64(src|q<<18|dl<<32|bin<<40);
// p2 per-bin CSR finalize + dinv + fused g0 = dinv(.)(x@W1) fp16.

#define NB1 768
#define NPB 256
#define MAXBINS 1024
#define TILE 4096
#define QS 16384.0f
#define QINV (1.0f / 16384.0f)

typedef _Float16 h2 __attribute__((ext_vector_type(2)));
typedef _Float16 h4 __attribute__((ext_vector_type(4)));
typedef _Float16 h8 __attribute__((ext_vector_type(8)));

__device__ __forceinline__ float sigmoidf_(float x) {
    return 1.0f / (1.0f + __expf(-x));
}

// ---- P1a: per-(bin,block) histogram via LDS
__global__ void p1a_hist(const int* __restrict__ dst, int* __restrict__ bh,
                         int ne, int nbins, int chunk) {
    __shared__ int h[MAXBINS];
    for (int k = threadIdx.x; k < nbins; k += 256) h[k] = 0;
    __syncthreads();
    int base = blockIdx.x * chunk;
    int end = min(base + chunk, ne);
    for (int e = base + threadIdx.x; e < end; e += 256)
        atomicAdd(&h[dst[e] >> 8], 1);
    __syncthreads();
    for (int k = threadIdx.x; k < nbins; k += 256)
        bh[(size_t)k * NB1 + blockIdx.x] = h[k];
}

// ---- S1: per-bin exclusive scan over NB1 block counts + bin totals
__global__ void s1_scan(int* __restrict__ bh, int* __restrict__ bintot) {
    __shared__ int sums[256];
    constexpr int W = NB1 / 256;
    int* row = bh + (size_t)blockIdx.x * NB1;
    int v[W];
    int s = 0;
#pragma unroll
    for (int j = 0; j < W; ++j) { v[j] = row[threadIdx.x * W + j]; s += v[j]; }
    sums[threadIdx.x] = s;
    __syncthreads();
    for (int o = 1; o < 256; o <<= 1) {
        int t = (threadIdx.x >= o) ? sums[threadIdx.x - o] : 0;
        __syncthreads();
        sums[threadIdx.x] += t;
        __syncthreads();
    }
    int excl = sums[threadIdx.x] - s;
#pragma unroll
    for (int j = 0; j < W; ++j) { row[threadIdx.x * W + j] = excl; excl += v[j]; }
    if (threadIdx.x == 255) bintot[blockIdx.x] = sums[255];
}

// ---- S2: exclusive scan of bin totals -> binbase
__global__ void s2_scan(const int* __restrict__ bintot, int* __restrict__ binbase,
                        int nbins, int ne) {
    __shared__ int tmp[1024];
    int tid = threadIdx.x;
    int v = (tid < nbins) ? bintot[tid] : 0;
    tmp[tid] = v;
    __syncthreads();
    for (int o = 1; o < 1024; o <<= 1) {
        int t = (tid >= o) ? tmp[tid - o] : 0;
        __syncthreads();
        tmp[tid] += t;
        __syncthreads();
    }
    if (tid < nbins) binbase[tid] = tmp[tid] - v;
    if (tid == 0) binbase[nbins] = ne;
}

// ---- P1b: LDS tile-sort + coalesced flush into bin-grouped u64 array
__global__ void p1b_scatter(const int* __restrict__ src, const int* __restrict__ dst,
                            const float* __restrict__ ew, const int* __restrict__ bh,
                            const int* __restrict__ binbase,
                            unsigned long long* __restrict__ b64,
                            int ne, int nbins, int chunk) {
    __shared__ unsigned long long stage[TILE];
    __shared__ int hist[MAXBINS];
    __shared__ int boff[MAXBINS];
    __shared__ int cur[MAXBINS];
    __shared__ int ssum[256];
    constexpr int MPT = TILE / 256;
    for (int k = threadIdx.x; k < nbins; k += 256)
        cur[k] = binbase[k] + bh[(size_t)k * NB1 + blockIdx.x];
    int base = blockIdx.x * chunk;
    int endb = min(base + chunk, ne);
    for (int t0 = base; t0 < endb; t0 += TILE) {
        int cnt = min(TILE, endb - t0);
        for (int k = threadIdx.x; k < nbins; k += 256) hist[k] = 0;
        __syncthreads();
        unsigned long long ent[MPT];
        int m = 0;
        for (int j = threadIdx.x; j < cnt; j += 256) {
            int e = t0 + j;
            int d = dst[e];
            float w = sigmoidf_(ew[e]);
            int q = (int)fminf(w * QS + 0.5f, 16383.0f);
            int b = d >> 8;
            ent[m++] = (unsigned long long)((unsigned)src[e] | ((unsigned)q << 18))
                     | ((unsigned long long)(d & 255) << 32)
                     | ((unsigned long long)b << 40);
            atomicAdd(&hist[b], 1);
        }
        __syncthreads();
        int w0 = threadIdx.x * 4;
        int lv[4];
        int ls = 0;
#pragma unroll
        for (int j = 0; j < 4; ++j) {
            int idx = w0 + j;
            lv[j] = (idx < nbins) ? hist[idx] : 0;
            ls += lv[j];
        }
        ssum[threadIdx.x] = ls;
        __syncthreads();
        for (int o = 1; o < 256; o <<= 1) {
            int t = (threadIdx.x >= o) ? ssum[threadIdx.x - o] : 0;
            __syncthreads();
            ssum[threadIdx.x] += t;
            __syncthreads();
        }
        int excl = ssum[threadIdx.x] - ls;
#pragma unroll
        for (int j = 0; j < 4; ++j) {
            int idx = w0 + j;
            if (idx < nbins) { boff[idx] = excl; excl += lv[j]; }
        }
        __syncthreads();
        for (int k = threadIdx.x; k < nbins; k += 256) hist[k] = 0;
        __syncthreads();
        for (int j = 0; j < m; ++j) {
            int b = (int)(ent[j] >> 40);
            int p = boff[b] + atomicAdd(&hist[b], 1);
            stage[p] = ent[j];
        }
        __syncthreads();
        for (int j = threadIdx.x; j < cnt; j += 256) {
            unsigned long long v = stage[j];
            int b = (int)(v >> 40);
            b64[cur[b] + (j - boff[b])] = v;
        }
        __syncthreads();
        for (int k = threadIdx.x; k < nbins; k += 256) cur[k] += hist[k];
        __syncthreads();
    }
}

// ---- P2: per-bin CSR finalize + dinv + fused g0 = dinv (.) (x @ W1) fp16
__global__ void p2_build(const unsigned long long* __restrict__ b64,
                         const int* __restrict__ binbase, unsigned* __restrict__ edata,
                         int* __restrict__ C, float* __restrict__ dinv,
                         const float* __restrict__ x, const float* __restrict__ W1,
                         _Float16* __restrict__ g0, int n, int ne, int nbins) {
    __shared__ int cnt[NPB];
    __shared__ int rs[NPB];
    __shared__ int curs[NPB];
    __shared__ unsigned qsum[NPB];
    __shared__ float Ws[56];
    if (threadIdx.x < 56) Ws[threadIdx.x] = W1[threadIdx.x];
    int b = blockIdx.x;
    int E0 = binbase[b], E1 = binbase[b + 1];
    cnt[threadIdx.x] = 0;
    qsum[threadIdx.x] = 0;
    __syncthreads();
    for (int k = E0 + threadIdx.x; k < E1; k += 256)
        atomicAdd(&cnt[(int)((b64[k] >> 32) & 0xFF)], 1);
    __syncthreads();
    int v = cnt[threadIdx.x];
    rs[threadIdx.x] = v;
    __syncthreads();
    for (int o = 1; o < NPB; o <<= 1) {
        int t = (threadIdx.x >= o) ? rs[threadIdx.x - o] : 0;
        __syncthreads();
        rs[threadIdx.x] += t;
        __syncthreads();
    }
    int excl = rs[threadIdx.x] - v;
    curs[threadIdx.x] = E0 + excl;
    int node = b * NPB + threadIdx.x;
    if (node < n) C[node] = E0 + excl;
    if (b == 0 && threadIdx.x == 0) C[n] = ne;
    __syncthreads();
    for (int k = E0 + threadIdx.x; k < E1; k += 256) {
        unsigned long long e64 = b64[k];
        int dl = (int)((e64 >> 32) & 0xFF);
        int pos = atomicAdd(&curs[dl], 1);
        edata[pos] = (unsigned)(e64 & 0xFFFFFFFFu);
        atomicAdd(&qsum[dl], (unsigned)((e64 >> 18) & 0x3FFFu));
    }
    __syncthreads();
    if (node < n) {
        float dv = rsqrtf((float)qsum[threadIdx.x] * QINV + 1.0f);
        dinv[node] = dv;
        float xi[7];
#pragma unroll
        for (int k = 0; k < 7; ++k) xi[k] = x[(size_t)node * 7 + k];
        h8 r;
#pragma unroll
        for (int o = 0; o < 8; ++o) {
            float acc = 0.0f;
#pragma unroll
            for (int k = 0; k < 7; ++k) acc = fmaf(xi[k], Ws[k * 8 + o], acc);
            r[o] = (_Float16)(acc * dv);
        }
        *reinterpret_cast<h8*>(g0 + (size_t)node * 8) = r;
    }
}

// ---- gather1 (quad/node, 2 feats/lane): g1 = dinv*relu(dinv*(g_i+sum sig*g_s)+b1)
__global__ void gather1_kernel(const _Float16* __restrict__ g, const float* __restrict__ dinv,
                               const int* __restrict__ C, const unsigned* __restrict__ edata,
                               const float* __restrict__ b1, _Float16* __restrict__ out, int n) {
    __shared__ float bs[8];
    if (threadIdx.x < 8) bs[threadIdx.x] = b1[threadIdx.x];
    __syncthreads();
    int t = blockIdx.x * blockDim.x + threadIdx.x;
    int i = t >> 2, sub = t & 3;
    if (i >= n) return;
    int beg = C[i], end = C[i + 1];
    h2 r0 = *reinterpret_cast<const h2*>(g + (size_t)i * 8 + sub * 2);
    float a0 = (float)r0[0], a1 = (float)r0[1];
    for (int k = beg; k < end; ++k) {
        unsigned v = edata[k];
        int s = (int)(v & 0x3FFFFu);
        float w = (float)(v >> 18) * QINV;
        h2 r = *reinterpret_cast<const h2*>(g + (size_t)s * 8 + sub * 2);
        a0 = fmaf((float)r[0], w, a0);
        a1 = fmaf((float)r[1], w, a1);
    }
    float dv = dinv[i];
    h2 o2;
    o2[0] = (_Float16)(dv * fmaxf(dv * a0 + bs[sub * 2 + 0], 0.0f));
    o2[1] = (_Float16)(dv * fmaxf(dv * a1 + bs[sub * 2 + 1], 0.0f));
    *reinterpret_cast<h2*>(out + (size_t)i * 8 + sub * 2) = o2;
}

// ---- gather2 (quad/node, 2 feats/lane) + fused dense 8->16 (4 outs/lane)
__global__ void gather2_kernel(const _Float16* __restrict__ g, const float* __restrict__ dinv,
                               const int* __restrict__ C, const unsigned* __restrict__ edata,
                               const float* __restrict__ W2, const float* __restrict__ b2,
                               _Float16* __restrict__ out, int n) {
    __shared__ float Ws[128];
    __shared__ float bs[16];
    if (threadIdx.x < 128) Ws[threadIdx.x] = W2[threadIdx.x];
    if (threadIdx.x < 16) bs[threadIdx.x] = b2[threadIdx.x];
    __syncthreads();
    int t = blockIdx.x * blockDim.x + threadIdx.x;
    int i = t >> 2, sub = t & 3;
    if (i >= n) return;
    int beg = C[i], end = C[i + 1];
    h2 r0 = *reinterpret_cast<const h2*>(g + (size_t)i * 8 + sub * 2);
    float acc[2] = {(float)r0[0], (float)r0[1]};
    for (int k = beg; k < end; ++k) {
        unsigned v = edata[k];
        int s = (int)(v & 0x3FFFFu);
        float w = (float)(v >> 18) * QINV;
        h2 r = *reinterpret_cast<const h2*>(g + (size_t)s * 8 + sub * 2);
        acc[0] = fmaf((float)r[0], w, acc[0]);
        acc[1] = fmaf((float)r[1], w, acc[1]);
    }
    float dv = dinv[i];
    acc[0] *= dv; acc[1] *= dv;  // raw2 slice (feats sub*2..+1)
    // rebuild full raw2[8] across the quad
    float pv[4], raw[8];
    int oo = (sub & 1) * 2;
#pragma unroll
    for (int j = 0; j < 2; ++j) {
        float o1 = __shfl_xor(acc[j], 1, 64);
        pv[oo + j] = acc[j];
        pv[(oo ^ 2) + j] = o1;
    }
    int pb = (sub & 2) * 2;
#pragma unroll
    for (int j = 0; j < 4; ++j) {
        float o2v = __shfl_xor(pv[j], 2, 64);
        raw[pb + j] = pv[j];
        raw[(pb ^ 4) + j] = o2v;
    }
    // dense: this lane computes outputs o = sub*4 .. sub*4+3
    h4 o4;
#pragma unroll
    for (int jo = 0; jo < 4; ++jo) {
        int o = sub * 4 + jo;
        float h = bs[o];
#pragma unroll
        for (int k = 0; k < 8; ++k) h = fmaf(raw[k], Ws[k * 16 + o], h);
        o4[jo] = (_Float16)(dv * fmaxf(h, 0.0f));
    }
    *reinterpret_cast<h4*>(out + (size_t)i * 16 + sub * 4) = o4;
}

// ---- gather3 (quad/node, 4 feats/lane) + fused dense 16->32 + head proj -> pq fp16
__global__ void gather3_kernel(const _Float16* __restrict__ g, const float* __restrict__ dinv,
                               const int* __restrict__ C, const unsigned* __restrict__ edata,
                               const float* __restrict__ W3, const float* __restrict__ b3,
                               const float* __restrict__ Wl1, const float* __restrict__ bl1,
                               const float* __restrict__ Wl2, const float* __restrict__ bl2,
                               _Float16* __restrict__ pqh, int n) {
    __shared__ float Ws[512];
    __shared__ float bs[32];
    __shared__ float wfs[192];
    __shared__ float bfs[3];
    for (int k = threadIdx.x; k < 512; k += 256) Ws[k] = W3[k];
    if (threadIdx.x < 32) bs[threadIdx.x] = b3[threadIdx.x];
    if (threadIdx.x < 192) {
        int f = threadIdx.x / 3, j = threadIdx.x % 3;
        float acc = 0.0f;
#pragma unroll
        for (int k = 0; k < 4; ++k) acc = fmaf(Wl1[f * 4 + k], Wl2[k * 3 + j], acc);
        wfs[threadIdx.x] = acc;
    }
    if (threadIdx.x < 3) {
        float acc = bl2[threadIdx.x];
#pragma unroll
        for (int k = 0; k < 4; ++k) acc = fmaf(bl1[k], Wl2[k * 3 + threadIdx.x], acc);
        bfs[threadIdx.x] = acc;
    }
    __syncthreads();
    int t = blockIdx.x * blockDim.x + threadIdx.x;
    int i = t >> 2, sub = t & 3;
    if (i >= n) return;
    int beg = C[i], end = C[i + 1];
    h4 r0 = *reinterpret_cast<const h4*>(g + (size_t)i * 16 + sub * 4);
    float acc[4];
#pragma unroll
    for (int j = 0; j < 4; ++j) acc[j] = (float)r0[j];
    for (int k = beg; k < end; ++k) {
        unsigned v = edata[k];
        int s = (int)(v & 0x3FFFFu);
        float w = (float)(v >> 18) * QINV;
        h4 r = *reinterpret_cast<const h4*>(g + (size_t)s * 16 + sub * 4);
#pragma unroll
        for (int j = 0; j < 4; ++j) acc[j] = fmaf((float)r[j], w, acc[j]);
    }
    float dv = dinv[i];
#pragma unroll
    for (int j = 0; j < 4; ++j) acc[j] *= dv;  // raw3 slice (feats sub*4..+3)
    // rebuild full raw3[16] across the quad
    float pv[8], raw[16];
    int oo = (sub & 1) * 4;
#pragma unroll
    for (int j = 0; j < 4; ++j) {
        float o1 = __shfl_xor(acc[j], 1, 64);
        pv[oo + j] = acc[j];
        pv[(oo ^ 4) + j] = o1;
    }
    int pb = (sub & 2) * 4;
#pragma unroll
    for (int j = 0; j < 8; ++j) {
        float o2v = __shfl_xor(pv[j], 2, 64);
        raw[pb + j] = pv[j];
        raw[(pb ^ 8) + j] = o2v;
    }
    // dense 16->32 + head projection; this lane handles o = sub*8 .. sub*8+7
    float p0 = (sub == 0) ? bfs[0] : 0.0f;
    float p1 = (sub == 0) ? bfs[1] : 0.0f;
    float p2 = (sub == 0) ? bfs[2] : 0.0f;
    float q0 = 0.0f, q1 = 0.0f, q2 = 0.0f;
#pragma unroll
    for (int jo = 0; jo < 8; ++jo) {
        int o = sub * 8 + jo;
        float h = bs[o];
#pragma unroll
        for (int k = 0; k < 16; ++k) h = fmaf(raw[k], Ws[k * 32 + o], h);
        h = fmaxf(h, 0.0f);
        p0 = fmaf(h, wfs[o * 3 + 0], p0);
        p1 = fmaf(h, wfs[o * 3 + 1], p1);
        p2 = fmaf(h, wfs[o * 3 + 2], p2);
        q0 = fmaf(h, wfs[(32 + o) * 3 + 0], q0);
        q1 = fmaf(h, wfs[(32 + o) * 3 + 1], q1);
        q2 = fmaf(h, wfs[(32 + o) * 3 + 2], q2);
    }
    // reduce across quad
    p0 += __shfl_xor(p0, 1, 64); p0 += __shfl_xor(p0, 2, 64);
    p1 += __shfl_xor(p1, 1, 64); p1 += __shfl_xor(p1, 2, 64);
    p2 += __shfl_xor(p2, 1, 64); p2 += __shfl_xor(p2, 2, 64);
    q0 += __shfl_xor(q0, 1, 64); q0 += __shfl_xor(q0, 2, 64);
    q1 += __shfl_xor(q1, 1, 64); q1 += __shfl_xor(q1, 2, 64);
    q2 += __shfl_xor(q2, 1, 64); q2 += __shfl_xor(q2, 2, 64);
    if (sub == 0) {
        h8 o8;
        o8[0] = (_Float16)p0; o8[1] = (_Float16)p1; o8[2] = (_Float16)p2; o8[3] = (_Float16)0.0f;
        o8[4] = (_Float16)q0; o8[5] = (_Float16)q1; o8[6] = (_Float16)q2; o8[7] = (_Float16)0.0f;
        *reinterpret_cast<h8*>(pqh + (size_t)i * 8) = o8;
    }
}

// ---- head: out[e] = p[a] + q[b]   (fp16 pq table, fp32 out)
__global__ void head_kernel(const int* __restrict__ w2b, const _Float16* __restrict__ pqh,
                            float* __restrict__ out, int nw) {
    int e = blockIdx.x * blockDim.x + threadIdx.x;
    if (e >= nw) return;
    int a = w2b[e];
    int b = w2b[(size_t)nw + e];
    h4 P = *reinterpret_cast<const h4*>(pqh + (size_t)a * 8);
    h4 Q = *reinterpret_cast<const h4*>(pqh + (size_t)b * 8 + 4);
    out[(size_t)e * 3 + 0] = (float)P[0] + (float)Q[0];
    out[(size_t)e * 3 + 1] = (float)P[1] + (float)Q[1];
    out[(size_t)e * 3 + 2] = (float)P[2] + (float)Q[2];
}

extern "C" void kernel_launch(void* const* d_in, const int* in_sizes, int n_in,
                              void* d_out, int out_size, void* d_ws, size_t ws_size,
                              hipStream_t stream) {
    const float* x   = (const float*)d_in[0];
    const int* eidx  = (const int*)d_in[1];
    const int* w2b   = (const int*)d_in[2];
    const float* ew  = (const float*)d_in[3];
    const float* W1  = (const float*)d_in[4];
    const float* b1  = (const float*)d_in[5];
    const float* W2  = (const float*)d_in[6];
    const float* b2  = (const float*)d_in[7];
    const float* W3  = (const float*)d_in[8];
    const float* b3  = (const float*)d_in[9];
    const float* Wl1 = (const float*)d_in[10];
    const float* bl1 = (const float*)d_in[11];
    const float* Wl2 = (const float*)d_in[12];
    const float* bl2 = (const float*)d_in[13];
    float* out = (float*)d_out;

    const int n  = in_sizes[0] / 7;   // 200000
    const int ne = in_sizes[1] / 2;   // 4000000
    const int nw = in_sizes[2] / 2;   // 2000000
    const int* src = eidx;
    const int* dst = eidx + ne;

    const int nbins = (n + NPB - 1) / NPB;    // 782
    const int chunk = (ne + NB1 - 1) / NB1;   // 5209

    // ---- workspace layout (4B words) ----
    float*     ws      = (float*)d_ws;
    float*     dinv    = ws;                                    // n
    int*       C       = (int*)(ws + n);                        // n+1 (+pad)
    unsigned*  edata   = (unsigned*)(ws + 2 * (size_t)n + 16);  // ne
    int*       bh      = (int*)(edata + ne);                    // nbins*NB1
    int*       bintot  = bh + (size_t)nbins * NB1;              // MAXBINS
    int*       binbase = bintot + MAXBINS;                      // MAXBINS
    _Float16*  g0      = (_Float16*)(binbase + MAXBINS);        // 8n halves (2n words)
    float*     bregion = (float*)(g0 + (size_t)n * 8);          // 2*ne words
    unsigned long long* b64 = (unsigned long long*)bregion;     // ne u64 (dead after p2)
    _Float16*  g1      = (_Float16*)bregion;                    // 8n halves  } alias
    _Float16*  g2      = (_Float16*)(bregion + 4 * (size_t)n);  // 16n halves } into
    _Float16*  pqh     = (_Float16*)(bregion + 12 * (size_t)n); // 8n halves  } b64

    const int Bl = 256;
    auto blks = [&](long long t) { return (int)((t + Bl - 1) / Bl); };
    const int nb4 = blks((long long)n * 4);  // quad-per-node grids

    // 1. CSR build (counting sort; tile-sorted write-combined scatter)
    p1a_hist<<<NB1, Bl, 0, stream>>>(dst, bh, ne, nbins, chunk);
    s1_scan<<<nbins, Bl, 0, stream>>>(bh, bintot);
    s2_scan<<<1, 1024, 0, stream>>>(bintot, binbase, nbins, ne);
    p1b_scatter<<<NB1, Bl, 0, stream>>>(src, dst, ew, bh, binbase, b64, ne, nbins, chunk);
    p2_build<<<nbins, Bl, 0, stream>>>(b64, binbase, edata, C, dinv, x, W1, g0, n, ne, nbins);

    // 2. three fused quad-per-node gather layers
    gather1_kernel<<<nb4, Bl, 0, stream>>>(g0, dinv, C, edata, b1, g1, n);
    gather2_kernel<<<nb4, Bl, 0, stream>>>(g1, dinv, C, edata, W2, b2, g2, n);
    gather3_kernel<<<nb4, Bl, 0, stream>>>(g2, dinv, C, edata, W3, b3,
                                           Wl1, bl1, Wl2, bl2, pqh, n);

    // 3. head
    head_kernel<<<blks(nw), Bl, 0, stream>>>(w2b, pqh, out, nw);
}